// Round 13
// baseline (149.471 us; speedup 1.0000x reference)
//
#include <hip/hip_runtime.h>
#include <hip/hip_bf16.h>

// One-hot: label (H*W int32) -> out (N, H, W) float32.
// Two-pass floor ~= 64R + 16W + 16R + 537W = 633 MB (~96-100 us at copy-class).
//
// Journal:
//  R1 (8 plane-streams/thread, read-once):    130 us (8 concurrent 64MiB-apart write windows = 4.6 TB/s)
//  R3 (nontemporal stores):                   250 us (nt bypasses L2 write-combine; never again)
//  R4 (plane per blockIdx.y, int32 reads):    146 us (single write window fast; label re-fetch thrash)
//  R5 (wave-per-plane, staggered):            153 us (8 concurrent aliased windows again)
//  R6 (pack u8 + 16px/thread expand):         185 us (per-THREAD-contiguous accesses broke coalescing)
//  R7 (pack u8 + plane-serial):               118 us (two-pass champion structure)
//  R8 (bitplanes v1):                         128 us (k2 fine; k1 had strided per-thread reads)
//  R9 (fused, NO phase lock):                 129 us (block drift -> R1 regime)
//  R10 (R7 + coalesced k1, fewer k2 WGs):     120 us (both factors immaterial)
//  R11 (4-bit pack, 8 MiB intermediate):      112 us (re-read shrunk but still 7x8MB = 56 MB)
//  R12 (cooperative grid.sync fusion):        FAILED (coop launch rejected in this env; output never
//                                              written. Cooperative path is unavailable -> two-pass forced)
//
// R13: bitplanes done right. Pass n reads ONLY its own 2 MiB bitmap, each
// byte exactly once -> re-read traffic 64->16 MB total, zero L3-retention
// dependence. k1 rebuilt around __ballot: lane-contiguous dword loads
// (256B/wave/instr), 3 ballots -> value bitplanes (uniform u64 in SGPRs),
// 17 scalar AND/NOTs -> 8 plane masks, lanes 0-15 store 16 u32s (64B/wave,
// consecutive wave-its fill adjacent 8B of the same lines -> L2 combines).
// k2 is R8's verified expand kernel, unchanged.

typedef unsigned int u32;
typedef unsigned long long u64;

// k1: block covers 4096 px; wave-it covers 64 consecutive px (1 dword/lane).
__global__ void __launch_bounds__(256) pack_bits_kernel(
    const int* __restrict__ label, u32* __restrict__ bits, int total) {
    const int words = total >> 5;
    const int lane  = threadIdx.x & 63;
    const int wv    = threadIdx.x >> 6;           // wave 0..3
    const long long base = (long long)blockIdx.x * 4096;

#pragma unroll
    for (int it = 0; it < 16; ++it) {
        const long long px0 = base + (it * 4 + wv) * 64;
        const int lab = label[px0 + lane];

        // value bitplanes (uniform across wave after ballot)
        u64 t0 = __ballot((lab & 1) != 0);
        u64 t1 = __ballot((lab & 2) != 0);
        u64 t2 = __ballot((lab & 4) != 0);
        u64 n0 = ~t0, n1 = ~t1, n2 = ~t2;

        u64 b0 = n2 & n1 & n0;
        u64 b1 = n2 & n1 & t0;
        u64 b2 = n2 & t1 & n0;
        u64 b3 = n2 & t1 & t0;
        u64 b4 = t2 & n1 & n0;
        u64 b5 = t2 & n1 & t0;
        u64 b6 = t2 & t1 & n0;
        u64 b7 = t2 & t1 & t0;

        if (lane < 16) {
            const int p = lane >> 1;              // plane
            // explicit select tree (no runtime-indexed array -> no scratch)
            u64 m = (p < 4) ? ((p < 2) ? (p == 0 ? b0 : b1) : (p == 2 ? b2 : b3))
                            : ((p < 6) ? (p == 4 ? b4 : b5) : (p == 6 ? b6 : b7));
            u32 v = (u32)(m >> ((lane & 1) * 32));
            bits[(long long)p * words + (px0 >> 5) + (lane & 1)] = v;
        }
    }
}

// k2 (verified in R8): one plane per blockIdx.y; block expands 8192 px.
// Per it: 32B/wave broadcast word load + lane-contiguous 1KiB/wave float4 store.
__global__ void __launch_bounds__(256) expand_bits_kernel(
    const u32* __restrict__ bits, float* __restrict__ out, int total) {
    const int n = blockIdx.y;
    const int tid = threadIdx.x;
    const int words = total >> 5;
    const u32* wp = bits + (long long)n * words + (long long)blockIdx.x * 256;
    float* op = out + (long long)n * total + (long long)blockIdx.x * 8192;
    const int sh = (tid & 7) * 4;
    const int wofs = tid >> 3;
#pragma unroll
    for (int it = 0; it < 8; ++it) {
        u32 w = wp[it * 32 + wofs];
        u32 nib = w >> sh;
        float4 v;
        v.x = (nib & 1u) ? 1.0f : 0.0f;
        v.y = (nib & 2u) ? 1.0f : 0.0f;
        v.z = (nib & 4u) ? 1.0f : 0.0f;
        v.w = (nib & 8u) ? 1.0f : 0.0f;
        *reinterpret_cast<float4*>(op + it * 1024 + tid * 4) = v;
    }
}

// Fallback (R1 structure) if N != 8 or shape doesn't divide.
__global__ void __launch_bounds__(256) get_one_hot_generic_kernel(
    const int* __restrict__ label, float* __restrict__ out,
    int total, int N) {
    long long i = ((long long)blockIdx.x * blockDim.x + threadIdx.x) * 4;
    if (i >= total) return;
    int4 lab = *reinterpret_cast<const int4*>(label + i);
    for (int n = 0; n < N; ++n) {
        float4 v;
        v.x = (lab.x == n) ? 1.0f : 0.0f;
        v.y = (lab.y == n) ? 1.0f : 0.0f;
        v.z = (lab.z == n) ? 1.0f : 0.0f;
        v.w = (lab.w == n) ? 1.0f : 0.0f;
        *reinterpret_cast<float4*>(out + (long long)n * total + i) = v;
    }
}

extern "C" void kernel_launch(void* const* d_in, const int* in_sizes, int n_in,
                              void* d_out, int out_size, void* d_ws, size_t ws_size,
                              hipStream_t stream) {
    const int* label = (const int*)d_in[0];
    float* out = (float*)d_out;

    int total = in_sizes[0];          // H*W = 16,777,216
    int N = out_size / total;         // 8

    // bitplane bytes = (total/32)*4*8 = total bytes
    bool fast = (N == 8) && (total % 8192 == 0) && (ws_size >= (size_t)total);
    if (fast) {
        pack_bits_kernel<<<total / 4096, 256, 0, stream>>>(label, (u32*)d_ws, total);
        dim3 grid(total / 8192, N);   // 2048 x 8; x fastest -> plane-serial sweep
        expand_bits_kernel<<<grid, 256, 0, stream>>>((const u32*)d_ws, out, total);
    } else {
        int grid = (total / 4 + 255) / 256;
        get_one_hot_generic_kernel<<<grid, 256, 0, stream>>>(label, out, total, N);
    }
}

// Round 14
// 136.496 us; speedup vs baseline: 1.0951x; 1.0951x over previous
//
#include <hip/hip_runtime.h>
#include <hip/hip_bf16.h>

// One-hot: label (H*W int32) -> out (N, H, W) float32.
// Two-pass floor ~= 64R + 16W + 16R + 537W = 633 MB (~96-102 us at copy-class).
//
// Journal:
//  R1 (8 plane-streams/thread, read-once):    130 us (8 concurrent 64MiB-apart write windows = 4.6 TB/s)
//  R3 (nontemporal stores):                   250 us (nt bypasses L2 write-combine; never again)
//  R4 (plane per blockIdx.y, int32 reads):    146 us (single write window fast; label re-fetch thrash)
//  R5 (wave-per-plane, staggered):            153 us (8 concurrent aliased windows again)
//  R6 (pack u8 + 16px/thread expand):         185 us (per-THREAD-contiguous accesses broke coalescing)
//  R7 (pack u8 + plane-serial):               118 us (two-pass champion structure)
//  R8 (bitplanes v1):                         128 us (k1 strided per-thread reads; k2 broadcast gmem reads)
//  R9 (fused, NO phase lock):                 129 us (block drift -> R1 regime)
//  R10 (R7 + coalesced k1, fewer k2 WGs):     120 us (both factors immaterial)
//  R11 (4-bit pack, 8 MiB intermediate):      112 us (re-read 64MB, partially L3-missing)
//  R12 (cooperative grid.sync fusion):        FAILED (coop launch rejected in this env -> two-pass forced)
//  R13 (bitplanes v2, ballot k1):             149 us (k1 store path: 16/64 lanes, 64B scattered stores)
//
// R14: bitplanes v3 — both prior defects engineered out.
//  k1: ballot -> plane masks, accumulate in LDS (8KB), final stores are 8
//      fully-coalesced 1KiB/wave instructions. All global reads 256B/wave.
//  k2: stage the block's 256 bitmap words in LDS via ONE coalesced u32
//      load/thread; broadcast reads from LDS; float4 stores unchanged.
//  Pass n reads only its own 2 MiB bitmap, each byte exactly once.

typedef unsigned int u32;
typedef unsigned long long u64;

#define K1_PX 8192   // px per k1 block (4 waves x 2048 px)
#define K2_PX 8192   // px per k2 block

// k1: wave wv covers px [wv*2048, wv*2048+2048) of the block's chunk,
// 32 iterations x 64 consecutive px (one dword/lane, 256B/wave).
__global__ void __launch_bounds__(256) pack_bits_kernel(
    const int* __restrict__ label, u32* __restrict__ bits, int total) {
    const int words = total >> 5;
    const int tid  = threadIdx.x;
    const int lane = tid & 63;
    const int wv   = tid >> 6;
    const long long base = (long long)blockIdx.x * K1_PX;

    __shared__ u32 lds[8][260];   // [plane][word-in-block], stride 260 spreads banks

    const int* lp = label + base + wv * 2048;
#pragma unroll 4
    for (int it = 0; it < 32; ++it) {
        const int lab = lp[it * 64 + lane];

        u64 t0 = __ballot((lab & 1) != 0);
        u64 t1 = __ballot((lab & 2) != 0);
        u64 t2 = __ballot((lab & 4) != 0);
        u64 n0 = ~t0, n1 = ~t1, n2 = ~t2;

        u64 b0 = n2 & n1 & n0, b1 = n2 & n1 & t0;
        u64 b2 = n2 & t1 & n0, b3 = n2 & t1 & t0;
        u64 b4 = t2 & n1 & n0, b5 = t2 & n1 & t0;
        u64 b6 = t2 & t1 & n0, b7 = t2 & t1 & t0;

        if (lane < 16) {
            const int p = lane >> 1;
            u64 m = (p < 4) ? ((p < 2) ? (p == 0 ? b0 : b1) : (p == 2 ? b2 : b3))
                            : ((p < 6) ? (p == 4 ? b4 : b5) : (p == 6 ? b6 : b7));
            lds[p][wv * 64 + it * 2 + (lane & 1)] = (u32)(m >> ((lane & 1) * 32));
        }
    }
    __syncthreads();

    // 8 coalesced stores: 256 lanes x u32 = 1KiB contiguous per plane.
    const long long wbase = base >> 5;
#pragma unroll
    for (int p = 0; p < 8; ++p) {
        bits[(long long)p * words + wbase + tid] = lds[p][tid];
    }
}

// k2: one plane per blockIdx.y (x fastest -> dispatcher-enforced plane-serial
// write windows). Stage 256 words in LDS (one coalesced load/thread), then
// 8 x (LDS broadcast read + lane-contiguous float4 store @1KiB/wave).
__global__ void __launch_bounds__(256) expand_bits_kernel(
    const u32* __restrict__ bits, float* __restrict__ out, int total) {
    const int n = blockIdx.y;
    const int tid = threadIdx.x;
    const int words = total >> 5;

    __shared__ u32 w[256];
    w[tid] = bits[(long long)n * words + (long long)blockIdx.x * 256 + tid];
    __syncthreads();

    float* op = out + (long long)n * total + (long long)blockIdx.x * K2_PX;
    const int sh = (tid & 7) * 4;
    const int widx = tid >> 3;
#pragma unroll
    for (int it = 0; it < 8; ++it) {
        u32 nib = w[it * 32 + widx] >> sh;
        float4 v;
        v.x = (nib & 1u) ? 1.0f : 0.0f;
        v.y = (nib & 2u) ? 1.0f : 0.0f;
        v.z = (nib & 4u) ? 1.0f : 0.0f;
        v.w = (nib & 8u) ? 1.0f : 0.0f;
        *reinterpret_cast<float4*>(op + it * 1024 + tid * 4) = v;
    }
}

// Fallback (R1 structure) if N != 8 or shape doesn't divide.
__global__ void __launch_bounds__(256) get_one_hot_generic_kernel(
    const int* __restrict__ label, float* __restrict__ out,
    int total, int N) {
    long long i = ((long long)blockIdx.x * blockDim.x + threadIdx.x) * 4;
    if (i >= total) return;
    int4 lab = *reinterpret_cast<const int4*>(label + i);
    for (int n = 0; n < N; ++n) {
        float4 v;
        v.x = (lab.x == n) ? 1.0f : 0.0f;
        v.y = (lab.y == n) ? 1.0f : 0.0f;
        v.z = (lab.z == n) ? 1.0f : 0.0f;
        v.w = (lab.w == n) ? 1.0f : 0.0f;
        *reinterpret_cast<float4*>(out + (long long)n * total + i) = v;
    }
}

extern "C" void kernel_launch(void* const* d_in, const int* in_sizes, int n_in,
                              void* d_out, int out_size, void* d_ws, size_t ws_size,
                              hipStream_t stream) {
    const int* label = (const int*)d_in[0];
    float* out = (float*)d_out;

    int total = in_sizes[0];          // H*W = 16,777,216
    int N = out_size / total;         // 8

    // bitplane bytes = (total/32)*4*8 = total bytes
    bool fast = (N == 8) && (total % K1_PX == 0) && (ws_size >= (size_t)total);
    if (fast) {
        pack_bits_kernel<<<total / K1_PX, 256, 0, stream>>>(label, (u32*)d_ws, total);
        dim3 grid(total / K2_PX, N);  // 2048 x 8; x fastest -> plane-serial sweep
        expand_bits_kernel<<<grid, 256, 0, stream>>>((const u32*)d_ws, out, total);
    } else {
        int grid = (total / 4 + 255) / 256;
        get_one_hot_generic_kernel<<<grid, 256, 0, stream>>>(label, out, total, N);
    }
}